// Round 1
// 1775.742 us; speedup vs baseline: 1.1641x; 1.1641x over previous
//
#include <hip/hip_runtime.h>
#include <hip/hip_bf16.h>

// TnoBlock2d: B=8, T=64, D=4, H=W=128, C=256, HM1=HM2=16, EPS=1e-5
// Inputs/outputs fp32. Internal cross-kernel tensors bf16, all accumulation fp32.
// d_out (128 MiB) doubles as k/q/v scratch during the attention phase.
//
//  K1  partial fwd DFT of x (fp32->bf16 stage) -> XF[512 bt][4 i][32 ky][16 kx]
//  K2  mode-mix + inverse DFT + skip -> k,q (later v) spatial bf16 (in d_out)
//  K3  S partials = q.k^T (chunked)        K4 softmax -> attn[8][64][64]
//  K4b convert end_skip fp32 -> bf16 (into dead Sp slice)
//  K5  out = attn @ v -> outg bf16 (ws)    K6 stats, K7 instnorm+gelu in place
//  K8  partial fwd DFT of outg -> GF (same buffer as XF)
//  K9  end mode-mix (256x256 complex per mode) -> EF (aliases Sp)
//  K10 end skip GEMM (256x256) via MFMA -> d_out fp32 (qkv dead by now)
//  K11 end inverse DFT, += into d_out

#define PI2 6.28318530717958647692f

typedef float f32x4 __attribute__((ext_vector_type(4)));
typedef __bf16 bf16x8 __attribute__((ext_vector_type(8)));

__device__ __forceinline__ float b2f(unsigned short u){ return __uint_as_float(((unsigned)u)<<16); }
__device__ __forceinline__ float lo2f(unsigned u){ return __uint_as_float(u<<16); }
__device__ __forceinline__ float hi2f(unsigned u){ return __uint_as_float(u & 0xffff0000u); }
__device__ __forceinline__ unsigned short f2b(float f){
  unsigned x = __float_as_uint(f);
  x += 0x7fffu + ((x>>16)&1u);          // RNE
  return (unsigned short)(x>>16);
}
__device__ __forceinline__ unsigned pack2(float a, float b){
  return (unsigned)f2b(a) | ((unsigned)f2b(b)<<16);
}
__device__ __forceinline__ void glds16(const void* g, void* l){
  __builtin_amdgcn_global_load_lds((__attribute__((address_space(1))) void*)g,
                                   (__attribute__((address_space(3))) void*)l, 16, 0, 0);
}

// ---------------- K1/K8: partial forward DFT of one 128x128 plane -------------
// out[ky,kx] = (1/16384) * sum_{h,w} x[h,w] e^{-2pi i (ky h + kx w)/128},
// ky in {0..15, 112..127} (stored as kyi 0..31), kx in 0..15.
template<bool F32>
__global__ __launch_bounds__(256)
void k_fwd_dft(const void* __restrict__ srcv,
               float* __restrict__ outr, float* __restrict__ outi)
{
  __shared__ unsigned short xs[16384];
  __shared__ float Xwr[2048], Xwi[2048];
  __shared__ float twc[128], tws[128];
  const int tid = threadIdx.x;
  const long plane = blockIdx.x;
  if (F32){
    const float4* p4 = (const float4*)((const float*)srcv + plane*16384);
    uint2* x2 = (uint2*)xs;
    for (int i=tid;i<4096;i+=256){
      float4 v = p4[i];
      x2[i] = make_uint2(pack2(v.x,v.y), pack2(v.z,v.w));
    }
  } else {
    const uint4* p4 = (const uint4*)((const unsigned short*)srcv + plane*16384);
    uint4* x4 = (uint4*)xs;
    for (int i=tid;i<2048;i+=256) x4[i] = p4[i];
  }
  if (tid < 128){
    float s,c; sincosf((float)tid*(PI2/128.0f), &s, &c);
    twc[tid]=c; tws[tid]=s;
  }
  __syncthreads();
  // stage 1: Xw[h][kx] = sum_w x[h][w] e^{-i 2pi kx w/128}
  const unsigned* xu = (const unsigned*)xs;
  for (int o=tid; o<2048; o+=256){
    int h = o >> 4, kx = o & 15;
    const unsigned* row = xu + h*64;
    float ar=0.f, ai=0.f;
    int m0 = 0, m1 = kx;
    const int step = (2*kx) & 127;
    for (int w2=0; w2<64; ++w2){
      unsigned u = row[w2];
      float a0 = lo2f(u), a1 = hi2f(u);
      ar = fmaf(a0, twc[m0], ar); ai = fmaf(-a0, tws[m0], ai);
      ar = fmaf(a1, twc[m1], ar); ai = fmaf(-a1, tws[m1], ai);
      m0 = (m0 + step) & 127; m1 = (m1 + step) & 127;
    }
    Xwr[o]=ar; Xwi[o]=ai;
  }
  __syncthreads();
  // stage 2: out[kyi][kx] = sum_h Xw[h][kx] e^{-i 2pi ky h/128} / 16384
  for (int o=tid; o<512; o+=256){
    int kyi = o >> 4, kx = o & 15;
    int ky = (kyi < 16) ? kyi : (kyi + 96);
    float ar=0.f, ai=0.f;
    int m = 0;
    const int step = ky & 127;
    for (int h=0; h<128; ++h){
      float A = Xwr[h*16+kx], B = Xwi[h*16+kx];
      float c = twc[m], s = tws[m];
      ar = fmaf(A, c, fmaf( B, s, ar));
      ai = fmaf(B, c, fmaf(-A, s, ai));
      m = (m + step) & 127;
    }
    outr[plane*512+o] = ar * (1.f/16384.f);
    outi[plane*512+o] = ai * (1.f/16384.f);
  }
}

// ---------------- K2: KQV mode mix + inverse DFT + skip ----------------------
// One block per (wblk, bt); produces 4 output channel planes (bf16).
// blk_off: 0 => blocks cover K(slot0),Q(slot1); 2 => V(slot0).
__global__ __launch_bounds__(256)
void k_kqv_synth(const float* __restrict__ xfr, const float* __restrict__ xfi,
                 const float* __restrict__ w1r, const float* __restrict__ w1i,
                 const float* __restrict__ w2r, const float* __restrict__ w2i,
                 const float* __restrict__ skw,
                 const float* __restrict__ x,
                 unsigned short* __restrict__ qkv, int blk_off)
{
  __shared__ float xr_s[2048], xi_s[2048];
  __shared__ float ofr[512], ofi[512];
  __shared__ float Zr[2048], Zi[2048];
  __shared__ float twc[128], tws[128];
  const int tid = threadIdx.x;
  const int slot = blockIdx.x >> 9;
  const int blk  = blk_off + slot;
  const int bt   = blockIdx.x & 511;
  for (int j=tid; j<2048; j+=256){
    xr_s[j] = xfr[(long)bt*2048 + j];
    xi_s[j] = xfi[(long)bt*2048 + j];
  }
  if (tid < 128){
    float s,c; sincosf((float)tid*(PI2/128.0f), &s, &c);
    twc[tid]=c; tws[tid]=s;
  }
  __syncthreads();
  for (int o=0; o<4; ++o){
    // mode mix: of[m] = sum_i xf[i][m] * w[i][o][m]  (w1 top rows, w2 bottom rows)
    for (int m=tid; m<512; m+=256){
      const int top = (m < 256);
      const float* wr = top ? w1r : w2r;
      const float* wi = top ? w1i : w2i;
      const int off = top ? m : (m-256);
      float ar=0.f, ai=0.f;
      #pragma unroll
      for (int i=0;i<4;++i){
        int widx = ((blk*4+i)*4+o)*256 + off;
        float wre = wr[widx], wim = wi[widx];
        float xr = xr_s[i*512+m], xi = xi_s[i*512+m];
        ar += xr*wre - xi*wim;
        ai += xr*wim + xi*wre;
      }
      ofr[m]=ar; ofi[m]=ai;
    }
    __syncthreads();
    // stage A: Z[h][kx] = sum_kyi of[kyi][kx] e^{+i 2pi ky h/128};  kx>0 prescaled by 2
    for (int z=tid; z<2048; z+=256){
      int h = z >> 4, kx = z & 15;
      float ar=0.f, ai=0.f;
      int m = 0;
      const int step = h;
      #pragma unroll
      for (int kyi=0; kyi<16; ++kyi){
        float A=ofr[kyi*16+kx], B=ofi[kyi*16+kx];
        float c=twc[m], s=tws[m];
        ar = fmaf(A,c,fmaf(-B,s,ar));
        ai = fmaf(A,s,fmaf( B,c,ai));
        m = (m+step)&127;
      }
      m = (112*h)&127;
      #pragma unroll
      for (int kyi=16; kyi<32; ++kyi){
        float A=ofr[kyi*16+kx], B=ofi[kyi*16+kx];
        float c=twc[m], s=tws[m];
        ar = fmaf(A,c,fmaf(-B,s,ar));
        ai = fmaf(A,s,fmaf( B,c,ai));
        m = (m+step)&127;
      }
      float sc = (kx==0) ? 1.f : 2.f;
      Zr[z]=ar*sc; Zi[z]=ai*sc;
    }
    __syncthreads();
    // stage B: y[h][w] = Re(Z[h][0]) + sum_{kx>=1} (Zr cos - Zi sin)  + skip (fp32 x)
    float sk0=skw[(blk*4+o)*4+0];
    float sk1=skw[(blk*4+o)*4+1];
    float sk2=skw[(blk*4+o)*4+2];
    float sk3=skw[(blk*4+o)*4+3];
    const float* xb = x + (long)bt*65536;
    unsigned short* ob = qkv + ((long)(slot*512+bt)*4 + o)*16384;
    for (int pix=tid; pix<16384; pix+=256){
      int h = pix >> 7, w = pix & 127;
      const float* Zrh = Zr + h*16;
      const float* Zih = Zi + h*16;
      float acc = Zrh[0];
      float cw = twc[w], sw = tws[w];
      float cr = cw, si = sw;                 // e^{+i 2pi kx w/128}, kx=1..
      #pragma unroll
      for (int kx=1; kx<16; ++kx){
        acc = fmaf(Zrh[kx], cr, fmaf(-Zih[kx], si, acc));
        float cr2 = cr*cw - si*sw;
        si = fmaf(cr, sw, si*cw);
        cr = cr2;
      }
      acc = fmaf(sk0, xb[pix        ], acc);
      acc = fmaf(sk1, xb[16384 + pix], acc);
      acc = fmaf(sk2, xb[32768 + pix], acc);
      acc = fmaf(sk3, xb[49152 + pix], acc);
      ob[pix] = f2b(acc);
    }
    __syncthreads();
  }
}

// ---------------- K3: S partials = q k^T over 256-element K-chunks -----------
__global__ __launch_bounds__(256)
void k_attn_qk(const unsigned short* __restrict__ qkv, float* __restrict__ Sp)
{
  __shared__ unsigned qs[8192], ks[8192];   // [j 128][t 64] (swizzled), j = uint pair
  const int tid = threadIdx.x;
  const int b = blockIdx.x >> 8, ch = blockIdx.x & 255;
  {
    const unsigned* qg = (const unsigned*)qkv + (long)(512 + b*64)*32768 + ch*128;
    const unsigned* kg = (const unsigned*)qkv + (long)(b*64)*32768 + ch*128;
    for (int i=tid; i<8192; i+=256){
      int t = i >> 7, j = i & 127;
      int sw = j*64 + ((t + j) & 63);       // swizzle: conflict-free transpose
      qs[sw] = qg[(long)t*32768 + j];
      ks[sw] = kg[(long)t*32768 + j];
    }
  }
  __syncthreads();
  const int t0 = (tid >> 4) << 2, s0 = (tid & 15) << 2;
  float acc[16];
  #pragma unroll
  for (int i=0;i<16;++i) acc[i]=0.f;
  for (int j=0; j<128; ++j){
    const unsigned* qrow = qs + j*64;
    const unsigned* krow = ks + j*64;
    float ql[4], qh[4], kl[4], kh[4];
    #pragma unroll
    for (int r=0;r<4;++r){ unsigned u=qrow[(t0+r+j)&63]; ql[r]=lo2f(u); qh[r]=hi2f(u); }
    #pragma unroll
    for (int c=0;c<4;++c){ unsigned u=krow[(s0+c+j)&63]; kl[c]=lo2f(u); kh[c]=hi2f(u); }
    #pragma unroll
    for (int r=0;r<4;++r)
      #pragma unroll
      for (int c=0;c<4;++c)
        acc[r*4+c] = fmaf(ql[r], kl[c], fmaf(qh[r], kh[c], acc[r*4+c]));
  }
  float* out = Sp + (long)(b*256+ch)*4096;
  #pragma unroll
  for (int r=0;r<4;++r)
    #pragma unroll
    for (int c=0;c<4;++c)
      out[(t0+r)*64 + s0+c] = acc[r*4+c];
}

// ---------------- K4: reduce chunks + softmax over s -------------------------
__global__ __launch_bounds__(64)
void k_softmax(const float* __restrict__ Sp, float* __restrict__ attn)
{
  const int s = threadIdx.x;
  const int b = blockIdx.x >> 6, t = blockIdx.x & 63;
  const float* base = Sp + (long)b*1048576 + t*64 + s;
  float acc = 0.f;
  for (int ch=0; ch<256; ++ch) acc += base[(long)ch*4096];
  acc *= (1.f/65536.f);
  float mx = acc;
  #pragma unroll
  for (int off=32; off; off>>=1) mx = fmaxf(mx, __shfl_xor(mx, off));
  float e = __expf(acc - mx);
  float sm = e;
  #pragma unroll
  for (int off=32; off; off>>=1) sm += __shfl_xor(sm, off);
  attn[(long)blockIdx.x*64 + s] = e / sm;
}

// ---------------- K4b: convert end skip weights fp32 -> bf16 [o][i] ----------
__global__ __launch_bounds__(256)
void k_conv_skip(const float* __restrict__ w, unsigned short* __restrict__ o)
{
  int i = (blockIdx.x*256 + threadIdx.x)*4;
  float4 v = *(const float4*)(w + i);
  uint2 r = make_uint2(pack2(v.x,v.y), pack2(v.z,v.w));
  *(uint2*)(o + i) = r;
}

// ---------------- K5: out = attn @ v (v in slot 0) ---------------------------
__global__ __launch_bounds__(256)
void k_attn_v(const unsigned short* __restrict__ qkv, const float* __restrict__ attn,
              unsigned short* __restrict__ outg)
{
  __shared__ float At[4096];                // transposed: [s][t]
  const int tid = threadIdx.x;
  const int pt = blockIdx.x & 15, d = (blockIdx.x>>4)&3, b = blockIdx.x>>6;
  for (int i=tid; i<4096; i+=256){
    int s = i >> 6, t = i & 63;
    At[i] = attn[(long)b*4096 + t*64 + s];
  }
  __syncthreads();
  const unsigned short* vb0 = qkv + ((long)(b*64)*4 + d)*16384;
  unsigned short* ob0 = outg + ((long)b*256 + d)*16384;
  for (int pass=0; pass<4; ++pass){
    int p = pt*1024 + pass*256 + tid;
    float acc[64];
    #pragma unroll
    for (int t=0;t<64;++t) acc[t]=0.f;
    for (int s=0; s<64; ++s){
      float vv = b2f(vb0[(long)s*65536 + p]);
      const float4* ar = (const float4*)(At + s*64);
      #pragma unroll
      for (int t4=0; t4<16; ++t4){
        float4 a = ar[t4];
        acc[t4*4+0] = fmaf(a.x, vv, acc[t4*4+0]);
        acc[t4*4+1] = fmaf(a.y, vv, acc[t4*4+1]);
        acc[t4*4+2] = fmaf(a.z, vv, acc[t4*4+2]);
        acc[t4*4+3] = fmaf(a.w, vv, acc[t4*4+3]);
      }
    }
    #pragma unroll
    for (int t=0;t<64;++t) ob0[(long)t*65536 + p] = f2b(acc[t]);
  }
}

// ---------------- K6: per-(b,c) mean / rstd ----------------------------------
__global__ __launch_bounds__(256)
void k_stats(const unsigned short* __restrict__ outg, float* __restrict__ stats)
{
  const int tid = threadIdx.x;
  const long plane = blockIdx.x;
  const unsigned* p = (const unsigned*)(outg + plane*16384);
  float s=0.f, q=0.f;
  for (int i=tid; i<8192; i+=256){
    unsigned u = p[i];
    float a = lo2f(u), b = hi2f(u);
    s += a + b; q = fmaf(a,a,fmaf(b,b,q));
  }
  __shared__ float red[8];
  #pragma unroll
  for (int off=32; off; off>>=1){ s += __shfl_xor(s, off); q += __shfl_xor(q, off); }
  if ((tid & 63) == 0){ red[tid>>6] = s; red[4 + (tid>>6)] = q; }
  __syncthreads();
  if (tid == 0){
    float S = red[0]+red[1]+red[2]+red[3];
    float Q = red[4]+red[5]+red[6]+red[7];
    float mu = S * (1.f/16384.f);
    float var = Q * (1.f/16384.f) - mu*mu;
    stats[plane*2]   = mu;
    stats[plane*2+1] = rsqrtf(var + 1e-5f);
  }
}

// ---------------- K7: instance norm + exact GELU, in place -------------------
__global__ __launch_bounds__(256)
void k_norm_gelu(unsigned short* __restrict__ outg, const float* __restrict__ stats)
{
  unsigned* p = (unsigned*)outg;
  int gi = blockIdx.x*256 + threadIdx.x;
  #pragma unroll
  for (int it=0; it<8; ++it){
    int idx = gi + it*2097152;
    int plane = idx >> 13;
    float mu = stats[plane*2], rs = stats[plane*2+1];
    unsigned u = p[idx];
    float a = (lo2f(u)-mu)*rs, b = (hi2f(u)-mu)*rs;
    a = 0.5f*a*(1.f + erff(a*0.70710678118654752f));
    b = 0.5f*b*(1.f + erff(b*0.70710678118654752f));
    p[idx] = pack2(a, b);
  }
}

// ---------------- K9: end mode mix: EF[b][o][m] = sum_i GF[b][i][m] w[i][o][m]
__global__ __launch_bounds__(256)
void k_end_mix(const float* __restrict__ gfr, const float* __restrict__ gfi,
               const float* __restrict__ w1r, const float* __restrict__ w1i,
               const float* __restrict__ w2r, const float* __restrict__ w2i,
               float* __restrict__ efr, float* __restrict__ efi)
{
  __shared__ float2 gbuf[2048];             // [ii 16][b 8][kx 16]
  const int tid = threadIdx.x;
  const int kyi = blockIdx.x >> 4, ot = blockIdx.x & 15;
  const int ol = tid >> 4, kx = tid & 15;
  const int o = ot*16 + ol;
  const float* wr = (kyi < 16) ? w1r : w2r;
  const float* wi = (kyi < 16) ? w1i : w2i;
  const int moff = (kyi & 15)*16 + kx;
  const int mode = kyi*16 + kx;
  float accr[8], acci[8];
  #pragma unroll
  for (int bb=0; bb<8; ++bb){ accr[bb]=0.f; acci[bb]=0.f; }
  for (int ic=0; ic<16; ++ic){
    __syncthreads();
    for (int e=tid; e<2048; e+=256){
      int ii = e >> 7, r = e & 127, bb = r >> 4, k2 = r & 15;
      long gidx = ((long)(bb*256 + ic*16 + ii))*512 + kyi*16 + k2;
      gbuf[e] = make_float2(gfr[gidx], gfi[gidx]);
    }
    __syncthreads();
    #pragma unroll 4
    for (int ii=0; ii<16; ++ii){
      int i = ic*16 + ii;
      long widx = ((long)i*256 + o)*256 + moff;
      float wre = wr[widx], wim = wi[widx];
      #pragma unroll
      for (int bb=0; bb<8; ++bb){
        float2 g = gbuf[ii*128 + bb*16 + kx];
        accr[bb] = fmaf(g.x, wre, fmaf(-g.y, wim, accr[bb]));
        acci[bb] = fmaf(g.x, wim, fmaf( g.y, wre, acci[bb]));
      }
    }
  }
  #pragma unroll
  for (int bb=0; bb<8; ++bb){
    long eidx = ((long)(bb*256 + o))*512 + mode;
    efr[eidx] = accr[bb];
    efi[eidx] = acci[bb];
  }
}

// ---------------- K10: end skip GEMM (256x256) via MFMA -> d_out fp32 --------
// out[b][o][p] = sum_i skb[o][i] * g[b][i][p]; M=256(o), K=256(i), N=64/block(p).
// A = skb bf16 [o][i] staged via global_load_lds into [256][32] LDS rows (64B).
// B = g bf16 [i][p]: reg-staged K-transpose into [64 p][32 k] LDS rows (64B).
// 4 waves, each owns 64(o) x 64(p) = 4x4 mfma_f32_16x16x32_bf16 fragments.
// Double-buffered, one __syncthreads per K-chunk (implicit vmcnt drain fences glds).
__global__ __launch_bounds__(256)
void k_end_skip_mfma(const unsigned short* __restrict__ g,
                     const unsigned short* __restrict__ skb,
                     float* __restrict__ outp)
{
  __shared__ unsigned short As[2][8192];    // [o 256][k 32], 16 KiB each
  __shared__ unsigned short Bs[2][2048];    // [p 64][k 32],   4 KiB each
  const int tid  = threadIdx.x;
  const int lane = tid & 63, wv = tid >> 6;
  const int l15  = lane & 15, rg = lane >> 4;
  const int b = blockIdx.x >> 8, pt = blockIdx.x & 255;

  // B staging: thread -> (p row, k segment); 8 scalar u16 global loads / chunk.
  const int bks = tid & 3;                  // k-seg (8 k each)
  const unsigned short* gcol = g + (long)b*4194304 + pt*64 + (tid >> 2);

  // A staging (glds): per-lane global src within a 16-row group.
  const int arow = lane >> 2;               // row within group
  const int acol = (lane & 3)*8;            // k elements within row

  f32x4 acc[4][4];
  #pragma unroll
  for (int mi=0; mi<4; ++mi)
    #pragma unroll
    for (int ni=0; ni<4; ++ni) acc[mi][ni] = (f32x4){0.f,0.f,0.f,0.f};

  unsigned br[8];
  // ---- prologue: stage chunk 0 ----
  #pragma unroll
  for (int j=0;j<8;++j) br[j] = gcol[(long)(bks*8 + j)*16384];
  #pragma unroll
  for (int q=0;q<4;++q){
    int row0 = (wv*4+q)*16;
    glds16(skb + (long)(row0 + arow)*256 + acol, &As[0][row0*32]);
  }
  {
    uint4 v;
    v.x = br[0]|(br[1]<<16); v.y = br[2]|(br[3]<<16);
    v.z = br[4]|(br[5]<<16); v.w = br[6]|(br[7]<<16);
    *(uint4*)&Bs[0][(tid>>2)*32 + bks*8] = v;
  }
  __syncthreads();

  #pragma unroll
  for (int t=0; t<8; ++t){
    const int cur = t & 1;
    if (t < 7){
      // issue next-chunk loads early: HBM latency hides under MFMA
      #pragma unroll
      for (int j=0;j<8;++j) br[j] = gcol[(long)((t+1)*32 + bks*8 + j)*16384];
      #pragma unroll
      for (int q=0;q<4;++q){
        int row0 = (wv*4+q)*16;
        glds16(skb + (long)(row0 + arow)*256 + (t+1)*32 + acol, &As[cur^1][row0*32]);
      }
    }
    bf16x8 af[4], bfr[4];
    #pragma unroll
    for (int mi=0;mi<4;++mi)
      af[mi] = *(const bf16x8*)&As[cur][(wv*64 + mi*16 + l15)*32 + rg*8];
    #pragma unroll
    for (int ni=0;ni<4;++ni)
      bfr[ni] = *(const bf16x8*)&Bs[cur][(ni*16 + l15)*32 + rg*8];
    #pragma unroll
    for (int mi=0;mi<4;++mi)
      #pragma unroll
      for (int ni=0;ni<4;++ni)
        acc[mi][ni] = __builtin_amdgcn_mfma_f32_16x16x32_bf16(af[mi], bfr[ni], acc[mi][ni], 0,0,0);
    if (t < 7){
      uint4 v;
      v.x = br[0]|(br[1]<<16); v.y = br[2]|(br[3]<<16);
      v.z = br[4]|(br[5]<<16); v.w = br[6]|(br[7]<<16);
      *(uint4*)&Bs[cur^1][(tid>>2)*32 + bks*8] = v;
    }
    __syncthreads();
  }

  // epilogue: D frag (mi,ni): col = ni*16 + (lane&15), row = mi*16 + (lane>>4)*4 + r
  float* ob = outp + (long)b*4194304 + pt*64;
  #pragma unroll
  for (int mi=0;mi<4;++mi){
    #pragma unroll
    for (int r=0;r<4;++r){
      int m = wv*64 + mi*16 + rg*4 + r;
      float* orow = ob + (long)m*16384;
      #pragma unroll
      for (int ni=0;ni<4;++ni)
        orow[ni*16 + l15] = acc[mi][ni][r];
    }
  }
}

// ---------------- K11: end inverse DFT, += into d_out ------------------------
__global__ __launch_bounds__(256)
void k_end_idft(const float* __restrict__ efr, const float* __restrict__ efi,
                float* __restrict__ outp)
{
  __shared__ float ofr[512], ofi[512];
  __shared__ float Zr[2048], Zi[2048];
  __shared__ float twc[128], tws[128];
  const int tid = threadIdx.x;
  const long plane = blockIdx.x;
  for (int m=tid; m<512; m+=256){ ofr[m]=efr[plane*512+m]; ofi[m]=efi[plane*512+m]; }
  if (tid < 128){
    float s,c; sincosf((float)tid*(PI2/128.0f), &s, &c);
    twc[tid]=c; tws[tid]=s;
  }
  __syncthreads();
  for (int z=tid; z<2048; z+=256){
    int h = z >> 4, kx = z & 15;
    float ar=0.f, ai=0.f;
    int m = 0;
    const int step = h;
    #pragma unroll
    for (int kyi=0; kyi<16; ++kyi){
      float A=ofr[kyi*16+kx], B=ofi[kyi*16+kx];
      float c=twc[m], s=tws[m];
      ar = fmaf(A,c,fmaf(-B,s,ar));
      ai = fmaf(A,s,fmaf( B,c,ai));
      m = (m+step)&127;
    }
    m = (112*h)&127;
    #pragma unroll
    for (int kyi=16; kyi<32; ++kyi){
      float A=ofr[kyi*16+kx], B=ofi[kyi*16+kx];
      float c=twc[m], s=tws[m];
      ar = fmaf(A,c,fmaf(-B,s,ar));
      ai = fmaf(A,s,fmaf( B,c,ai));
      m = (m+step)&127;
    }
    float sc = (kx==0) ? 1.f : 2.f;
    Zr[z]=ar*sc; Zi[z]=ai*sc;
  }
  __syncthreads();
  for (int pix=tid; pix<16384; pix+=256){
    int h = pix >> 7, w = pix & 127;
    const float* Zrh = Zr + h*16;
    const float* Zih = Zi + h*16;
    float acc = Zrh[0];
    float cw = twc[w], sw = tws[w];
    float cr = cw, si = sw;
    #pragma unroll
    for (int kx=1; kx<16; ++kx){
      acc = fmaf(Zrh[kx], cr, fmaf(-Zih[kx], si, acc));
      float cr2 = cr*cw - si*sw;
      si = fmaf(cr, sw, si*cw);
      cr = cr2;
    }
    outp[plane*16384 + pix] += acc;
  }
}

// -----------------------------------------------------------------------------
extern "C" void kernel_launch(void* const* d_in, const int* in_sizes, int n_in,
                              void* d_out, int out_size, void* d_ws, size_t ws_size,
                              hipStream_t stream) {
  const float* x     = (const float*)d_in[0];
  const float* kw1r  = (const float*)d_in[1];
  const float* kw1i  = (const float*)d_in[2];
  const float* kw2r  = (const float*)d_in[3];
  const float* kw2i  = (const float*)d_in[4];
  const float* kskip = (const float*)d_in[5];
  const float* ew1r  = (const float*)d_in[6];
  const float* ew1i  = (const float*)d_in[7];
  const float* ew2r  = (const float*)d_in[8];
  const float* ew2i  = (const float*)d_in[9];
  const float* eskip = (const float*)d_in[10];
  float* outp = (float*)d_out;

  // d_out (128 MiB) = k/q/v bf16 scratch during attention phase, dead before K10.
  unsigned short* qkv = (unsigned short*)d_out;    // slot0 = k then v, slot1 = q

  // workspace (~104.2 MiB)
  char* ws = (char*)d_ws;
  float* XFr   = (float*)ws;                       //  4 MiB (also GF re)
  float* XFi   = XFr + 1048576;                    //  4 MiB (also GF im)
  float* Sp    = XFi + 1048576;                    // 32 MiB S partials [8][256][64][64]
  float* EFr   = Sp;                               //  aliases Sp (dead after softmax)
  float* EFi   = Sp + 1048576;
  unsigned short* skb = (unsigned short*)(Sp + 3145728); // 128 KiB bf16 end-skip (dead Sp slice, clear of EF)
  float* attn  = Sp + 8388608;                     // 128 KiB [8][64][64]
  float* stats = attn + 32768;                     //  16 KiB [2048][mu,rstd]
  unsigned short* outg = (unsigned short*)(stats + 4096);  // 64 MiB bf16

  k_fwd_dft<true>  <<<2048, 256, 0, stream>>>(x, XFr, XFi);
  k_kqv_synth      <<<1024, 256, 0, stream>>>(XFr, XFi, kw1r, kw1i, kw2r, kw2i, kskip, x, qkv, 0); // k,q
  k_attn_qk        <<<2048, 256, 0, stream>>>(qkv, Sp);
  k_softmax        <<< 512,  64, 0, stream>>>(Sp, attn);
  k_conv_skip      <<<  64, 256, 0, stream>>>(eskip, skb);                     // Sp dead -> safe
  k_kqv_synth      <<< 512, 256, 0, stream>>>(XFr, XFi, kw1r, kw1i, kw2r, kw2i, kskip, x, qkv, 2); // v
  k_attn_v         <<< 512, 256, 0, stream>>>(qkv, attn, outg);
  k_stats          <<<2048, 256, 0, stream>>>(outg, stats);
  k_norm_gelu      <<<8192, 256, 0, stream>>>(outg, stats);
  k_fwd_dft<false> <<<2048, 256, 0, stream>>>(outg, XFr, XFi);                 // GF
  k_end_mix        <<< 512, 256, 0, stream>>>(XFr, XFi, ew1r, ew1i, ew2r, ew2i, EFr, EFi);
  k_end_skip_mfma  <<<2048, 256, 0, stream>>>(outg, skb, outp);                // writes d_out
  k_end_idft       <<<2048, 256, 0, stream>>>(EFr, EFi, outp);                 // += spectral
}